// Round 12
// baseline (64.757 us; speedup 1.0000x reference)
//
#include <hip/hip_runtime.h>
#include <math.h>

#define BB 4
#define SS 4096
#define HH 1024
#define NH 16
#define DK 64
#define NMODES 4
#define NSB 128             // s-chunks for DFT kernel
#define SCHUNK (SS/NSB)     // 32
#define PPLANE ((size_t)BB * NSB * HH)   // one q-plane of P: 512K floats
#define TWO_PI 6.28318530717958647692f

typedef float nfloat4 __attribute__((ext_vector_type(4)));  // native vec for nontemporal

// ---------------- Kernel A: partial 4-mode DFT of x over s ----------------
// 512 blocks x 256 thr, each block reads 32 FULL 4 KB rows (contiguous
// float4 per wave). P stored as 8 planes: P[q*PPLANE + (b*NSB+sb)*HH + c].
__global__ __launch_bounds__(256) void kA_dft(const float* __restrict__ x,
                                              const int* __restrict__ index,
                                              float* __restrict__ P) {
    __shared__ float tab[SCHUNK * 8];
    int t  = threadIdx.x;
    int sb = blockIdx.x & (NSB - 1);
    int b  = blockIdx.x >> 7;

    // fill trig table: 32 rows x 4 modes = 128 entries
    if (t < SCHUNK * NMODES) {
        int sl = t >> 2, m = t & 3;
        int k  = index[m];
        int sv = sb * SCHUNK + sl;
        int r  = (k * sv) & (SS - 1);          // exact phase mod S
        float ang = (float)r * (TWO_PI / (float)SS);
        float sn, cs;
        sincosf(ang, &sn, &cs);
        tab[sl * 8 + m * 2]     = cs;
        tab[sl * 8 + m * 2 + 1] = sn;
    }
    __syncthreads();

    int c0 = t * 4;
    float acc[4][8];
    #pragma unroll
    for (int e = 0; e < 4; ++e)
        #pragma unroll
        for (int q = 0; q < 8; ++q) acc[e][q] = 0.f;

    const float* xp = x + ((size_t)(b * SS + sb * SCHUNK)) * HH + c0;
    #pragma unroll 8
    for (int r = 0; r < SCHUNK; ++r) {
        float4 xv = *(const float4*)(xp + (size_t)r * HH);
        float4 t0 = *(const float4*)&tab[r * 8];      // broadcast (uniform addr)
        float4 t1 = *(const float4*)&tab[r * 8 + 4];
        float xe;
        #pragma unroll
        for (int e = 0; e < 4; ++e) {
            xe = (e == 0) ? xv.x : (e == 1) ? xv.y : (e == 2) ? xv.z : xv.w;
            acc[e][0] += xe * t0.x;  acc[e][1] -= xe * t0.y;  // G = sum x*(cos - i sin)
            acc[e][2] += xe * t0.z;  acc[e][3] -= xe * t0.w;
            acc[e][4] += xe * t1.x;  acc[e][5] -= xe * t1.y;
            acc[e][6] += xe * t1.z;  acc[e][7] -= xe * t1.w;
        }
    }
    size_t base = (size_t)(b * NSB + sb) * HH + c0;
    #pragma unroll
    for (int q = 0; q < 8; ++q) {
        *(float4*)&P[q * PPLANE + base] =
            make_float4(acc[0][q], acc[1][q], acc[2][q], acc[3][q]);
    }
}

// ---------------- Kernel A2: coalesced partial reduction ------------------
// 256 blocks x 256 thr; thread owns a float4 of j and one s-octant (16 sb).
// Every wave load/store is one contiguous 1 KB segment.
// Gp8[((b*8+oct)*8+q)*HH + j]  (8 octant-partials per (b,q,j))
__global__ __launch_bounds__(256) void kA2_reduce(const float* __restrict__ P,
                                                  float* __restrict__ Gp8) {
    int i  = blockIdx.x * 256 + threadIdx.x;  // 0..65535
    int j4 = i & 255;
    int q  = (i >> 8) & 7;
    int oct = (i >> 11) & 7;
    int b  = i >> 14;
    const float4* pp = (const float4*)(P + (size_t)q * PPLANE
                     + (size_t)(b * NSB + oct * 16) * HH) + j4;
    float4 s = make_float4(0.f, 0.f, 0.f, 0.f);
    #pragma unroll
    for (int sb = 0; sb < 16; ++sb) {
        float4 v = pp[(size_t)sb * (HH / 4)];
        s.x += v.x; s.y += v.y; s.z += v.z; s.w += v.w;
    }
    *(float4*)&Gp8[((size_t)((b * 8 + oct) * 8 + q)) * HH + j4 * 4] = s;
}

// ---------------- Kernel BC: octant-sum + projection + mode-mix -----------
// 64 blocks (b,h) x 512 thr.
// Phase 0: Gs[q][j] = sum of 8 octant partials (1 KB coalesced loads)
// Phase 1: xm[c,:] = Wq[c,:] . G  for c in head h (64 ch, 8-way j-split)
// Phase 2: complex mode-mix -> irfft coefficients CF
__global__ __launch_bounds__(512) void kBC(const float* __restrict__ Gp8,
                                           const float* __restrict__ Wq,
                                           const float* __restrict__ bq,
                                           const int* __restrict__ index,
                                           const float* __restrict__ wr,
                                           const float* __restrict__ wi,
                                           float* __restrict__ CF) {
    __shared__ float Gs[8 * HH];         // 32 KB
    __shared__ float xs[DK * 8];         // 2 KB
    __shared__ float red[8][DK][9];      // 18 KB, padded
    int t = threadIdx.x;
    int h = blockIdx.x & 15;
    int b = blockIdx.x >> 4;

    // ---- Phase 0: sum 8 octant partials into LDS ----
    #pragma unroll
    for (int k = 0; k < 4; ++k) {
        int u = t + 512 * k;             // 0..2047
        int q = u >> 8, j4 = u & 255;
        float4 s = make_float4(0.f, 0.f, 0.f, 0.f);
        #pragma unroll
        for (int oct = 0; oct < 8; ++oct) {
            float4 v = *(const float4*)&Gp8[
                ((size_t)((b * 8 + oct) * 8 + q)) * HH + j4 * 4];
            s.x += v.x; s.y += v.y; s.z += v.z; s.w += v.w;
        }
        *(float4*)&Gs[q * HH + j4 * 4] = s;
    }
    __syncthreads();

    // ---- Phase 1: projection for this head's 64 channels ----
    {
        int cl = t >> 3, jq = t & 7;
        int c = h * DK + cl;
        float acc[8] = {0.f,0.f,0.f,0.f,0.f,0.f,0.f,0.f};
        for (int j0 = jq * 4; j0 < HH; j0 += 32) {
            float4 wv = *(const float4*)&Wq[(size_t)c * HH + j0];
            #pragma unroll
            for (int q = 0; q < 8; ++q) {
                float4 gv = *(const float4*)&Gs[q * HH + j0];
                acc[q] += wv.x * gv.x + wv.y * gv.y + wv.z * gv.z + wv.w * gv.w;
            }
        }
        #pragma unroll
        for (int q = 0; q < 8; ++q) {
            acc[q] += __shfl_xor(acc[q], 1);
            acc[q] += __shfl_xor(acc[q], 2);
            acc[q] += __shfl_xor(acc[q], 4);
        }
        if (jq == 0) {
            float bias = bq[c];
            #pragma unroll
            for (int m = 0; m < NMODES; ++m)
                if (index[m] == 0) acc[2 * m] += bias * (float)SS;  // sum_s e^0 = S
            #pragma unroll
            for (int q = 0; q < 8; ++q) xs[cl * 8 + q] = acc[q];
        }
    }
    __syncthreads();

    // ---- Phase 2: complex mode-mix -> irfft coefficients ----
    {
        int o = t & 63, iq = t >> 6;     // 8-way i-split
        float re[4] = {0.f,0.f,0.f,0.f}, im[4] = {0.f,0.f,0.f,0.f};
        #pragma unroll
        for (int ii = 0; ii < 8; ++ii) {
            int i = iq * 8 + ii;
            float4 wrv = *(const float4*)&wr[(((size_t)(h * DK + i)) * DK + o) * 4];
            float4 wiv = *(const float4*)&wi[(((size_t)(h * DK + i)) * DK + o) * 4];
            float xr, xi;
            xr = xs[i * 8 + 0]; xi = xs[i * 8 + 1];
            re[0] += xr * wrv.x - xi * wiv.x;  im[0] += xr * wiv.x + xi * wrv.x;
            xr = xs[i * 8 + 2]; xi = xs[i * 8 + 3];
            re[1] += xr * wrv.y - xi * wiv.y;  im[1] += xr * wiv.y + xi * wrv.y;
            xr = xs[i * 8 + 4]; xi = xs[i * 8 + 5];
            re[2] += xr * wrv.z - xi * wiv.z;  im[2] += xr * wiv.z + xi * wrv.z;
            xr = xs[i * 8 + 6]; xi = xs[i * 8 + 7];
            re[3] += xr * wrv.w - xi * wiv.w;  im[3] += xr * wiv.w + xi * wrv.w;
        }
        #pragma unroll
        for (int m = 0; m < 4; ++m) {
            red[iq][o][2 * m]     = re[m];
            red[iq][o][2 * m + 1] = im[m];
        }
        __syncthreads();
        if (iq == 0) {
            float rr[8];
            #pragma unroll
            for (int q = 0; q < 8; ++q) {
                float s = 0.f;
                #pragma unroll
                for (int g = 0; g < 8; ++g) s += red[g][o][q];
                rr[q] = s;
            }
            int co = o * NH + h;         // faithful permute(0,3,2,1) flatten
            const float inv = 1.0f / (float)SS;
            float* cp = CF + ((size_t)(b * HH + co)) * 8;
            cp[0] =  rr[0] * inv;        // irfft ignores Im(c0) (pocketfft c2r)
            cp[1] =  2.0f * rr[2] * inv;
            cp[2] = -2.0f * rr[3] * inv;
            cp[3] =  2.0f * rr[4] * inv;
            cp[4] = -2.0f * rr[5] * inv;
            cp[5] =  2.0f * rr[6] * inv;
            cp[6] = -2.0f * rr[7] * inv;
            cp[7] =  0.0f;
        }
    }
}

// ---------------- Kernel D: low-rank irfft + residual + LayerNorm ---------
// 8 rows/block; x loads issued first; nontemporal out stores.
#define KD_ROWS 8
__global__ __launch_bounds__(256) void kD_out(const float* __restrict__ x,
                                              const float* __restrict__ CF,
                                              const float* __restrict__ gamma,
                                              const float* __restrict__ beta,
                                              float* __restrict__ out) {
    __shared__ float red[4][KD_ROWS][2];
    int t  = threadIdx.x;
    int b  = blockIdx.x >> 9;
    int s0 = (blockIdx.x & 511) * KD_ROWS;
    int c0 = t * 4;
    int w = t >> 6, lane = t & 63;

    // issue the long-latency x loads first
    float4 yv[KD_ROWS];
    #pragma unroll
    for (int r = 0; r < KD_ROWS; ++r) {
        int s = s0 + r;
        yv[r] = *(const float4*)&x[((size_t)(b * SS + s)) * HH + c0];
    }

    float myc, mys;
    {
        float ang = (float)(s0 + (t & 7)) * (TWO_PI / (float)SS);
        sincosf(ang, &mys, &myc);
    }

    const float* cp = CF + (size_t)b * HH * 8 + (size_t)c0 * 8;
    float4 cfa[8];
    #pragma unroll
    for (int e = 0; e < 4; ++e) {
        cfa[2 * e]     = *(const float4*)(cp + e * 8);
        cfa[2 * e + 1] = *(const float4*)(cp + e * 8 + 4);
    }
    float4 g4 = *(const float4*)&gamma[c0];
    float4 b4 = *(const float4*)&beta[c0];

    float sm[KD_ROWS], sq[KD_ROWS];
    #pragma unroll
    for (int r = 0; r < KD_ROWS; ++r) {
        float c1 = __shfl(myc, r), s1 = __shfl(mys, r);
        float c2 = c1 * c1 - s1 * s1, s2 = 2.f * s1 * c1;
        float c3 = c2 * c1 - s2 * s1, s3 = s2 * c1 + c2 * s1;
        float ye[4];
        #pragma unroll
        for (int e = 0; e < 4; ++e) {
            float xe = (e == 0) ? yv[r].x : (e == 1) ? yv[r].y
                     : (e == 2) ? yv[r].z : yv[r].w;
            float4 A = cfa[2 * e], Bv = cfa[2 * e + 1];
            ye[e] = xe + A.x + A.y * c1 + A.z * s1 + A.w * c2
                       + Bv.x * s2 + Bv.y * c3 + Bv.z * s3;
        }
        yv[r] = make_float4(ye[0], ye[1], ye[2], ye[3]);
        sm[r] = ye[0] + ye[1] + ye[2] + ye[3];
        sq[r] = ye[0]*ye[0] + ye[1]*ye[1] + ye[2]*ye[2] + ye[3]*ye[3];
    }
    #pragma unroll
    for (int off = 1; off < 64; off <<= 1) {
        #pragma unroll
        for (int r = 0; r < KD_ROWS; ++r) {
            sm[r] += __shfl_xor(sm[r], off);
            sq[r] += __shfl_xor(sq[r], off);
        }
    }
    if (lane == 0) {
        #pragma unroll
        for (int r = 0; r < KD_ROWS; ++r) {
            red[w][r][0] = sm[r];
            red[w][r][1] = sq[r];
        }
    }
    __syncthreads();
    #pragma unroll
    for (int r = 0; r < KD_ROWS; ++r) {
        int s = s0 + r;
        float tot  = red[0][r][0] + red[1][r][0] + red[2][r][0] + red[3][r][0];
        float totq = red[0][r][1] + red[1][r][1] + red[2][r][1] + red[3][r][1];
        float mean = tot * (1.0f / (float)HH);
        float var  = totq * (1.0f / (float)HH) - mean * mean;
        float rs = rsqrtf(var + 1e-5f);
        nfloat4 o4;
        o4.x = (yv[r].x - mean) * rs * g4.x + b4.x;
        o4.y = (yv[r].y - mean) * rs * g4.y + b4.y;
        o4.z = (yv[r].z - mean) * rs * g4.z + b4.z;
        o4.w = (yv[r].w - mean) * rs * g4.w + b4.w;
        __builtin_nontemporal_store(o4,
            (nfloat4*)&out[((size_t)(b * SS + s)) * HH + c0]);
    }
}

extern "C" void kernel_launch(void* const* d_in, const int* in_sizes, int n_in,
                              void* d_out, int out_size, void* d_ws, size_t ws_size,
                              hipStream_t stream) {
    const float* x     = (const float*)d_in[0];
    const float* Wq    = (const float*)d_in[1];
    const float* bq    = (const float*)d_in[2];
    const float* wr    = (const float*)d_in[3];
    const float* wi    = (const float*)d_in[4];
    const float* gamma = (const float*)d_in[5];
    const float* beta  = (const float*)d_in[6];
    const int*   index = (const int*)d_in[7];
    float* out = (float*)d_out;
    float* ws  = (float*)d_ws;

    const size_t nP   = PPLANE * 8;              // 4M floats (16 MB)
    const size_t nGp8 = (size_t)BB * 8 * 8 * HH; // 256K floats (1 MB)
    const size_t nCF  = (size_t)BB * HH * 8;     // 32K floats (128 KB)

    float *P, *Gp8, *CFb;
    if (ws_size >= (nP + nGp8 + nCF) * sizeof(float)) {
        P   = ws;
        Gp8 = P + nP;
        CFb = Gp8 + nGp8;
    } else {
        // fallback: P lives in d_out (consumed by kA2 before kD writes out)
        P   = out;
        Gp8 = ws;
        CFb = Gp8 + nGp8;
    }

    hipLaunchKernelGGL(kA_dft,     dim3(BB * NSB), dim3(256), 0, stream, x, index, P);
    hipLaunchKernelGGL(kA2_reduce, dim3(256), dim3(256), 0, stream, P, Gp8);
    hipLaunchKernelGGL(kBC,        dim3(BB * NH), dim3(512), 0, stream,
                       Gp8, Wq, bq, index, wr, wi, CFb);
    hipLaunchKernelGGL(kD_out,     dim3(BB * (SS / KD_ROWS)), dim3(256), 0, stream,
                       x, CFb, gamma, beta, out);
}